// Round 8
// baseline (2189.428 us; speedup 1.0000x reference)
//
#include <hip/hip_runtime.h>
#include <math.h>

typedef short short8 __attribute__((ext_vector_type(8)));
typedef float f32x4 __attribute__((ext_vector_type(4)));
typedef unsigned short u16;
typedef unsigned int u32;

#define GAS(p) ((__attribute__((address_space(1))) void*)(p))
#define LAS(p) ((__attribute__((address_space(3))) void*)(p))

namespace {

constexpr int HW   = 1440;           // 18*80
constexpr int PBAT = 20 * 82 * 1024; // padded per-batch elems

__device__ __forceinline__ u16 f2bf(float f) {
  u32 u = __float_as_uint(f);
  return (u16)((u + 0x7FFFu + ((u >> 16) & 1u)) >> 16);
}
__device__ __forceinline__ float bf2f(u16 h) {
  return __uint_as_float(((u32)h) << 16);
}

// XCD-aware bijective remap (m204): dispatch id -> virt; each of 8 XCDs
// (id%8 under round-robin) owns a CONTIGUOUS virt range, decoded px-major.
// (R6 verified: FETCH 958->222 MB.)
__device__ __forceinline__ int xcd_virt(int id, int N) {
  int q = N >> 3, r = N & 7;
  int xcd = id & 7, pos = id >> 3;
  return (xcd < r ? xcd * (q + 1) : r * (q + 1) + (xcd - r) * q) + pos;
}

// ---------------- NCHW fp32 -> padded NHWC bf16 ----------------
__global__ __launch_bounds__(256)
void transpose_feat(const float* __restrict__ src, u16* __restrict__ dst) {
  __shared__ float tile[128][17];
  const int bh = blockIdx.y;            // 0..143
  const int b = bh / 18, h = bh % 18;
  const int wt = blockIdx.x % 5, ct = blockIdx.x / 5;
  const int w0 = wt * 16, c0 = ct * 128;
  const int tid = threadIdx.x;
#pragma unroll
  for (int it = 0; it < 8; ++it) {
    int idx = it * 256 + tid;
    int c = idx >> 4, w = idx & 15;
    tile[c][w] = src[((size_t)(b * 1024 + c0 + c) * 18 + h) * 80 + w0 + w];
  }
  __syncthreads();
  const int px = tid >> 4, cq = tid & 15;
  union { uint4 u; u16 s[8]; } pk;
#pragma unroll
  for (int j = 0; j < 8; ++j) pk.s[j] = f2bf(tile[cq * 8 + j][px]);
  *(uint4*)(dst + ((size_t)(b * 20 + h + 1) * 82 + (w0 + px + 1)) * 1024 + c0 + cq * 8) = pk.u;
}

// ---------------- merged weight repack: 7 tensors in one dispatch ----------------
struct RepackArgs {
  const float* src[7];
  u16* dst[7];
  int O[7];
  int start[7];
  int nseg;
};

__global__ __launch_bounds__(256)
void repack_all(RepackArgs ra) {
  int blk = blockIdx.x;
  int seg = 0;
#pragma unroll
  for (int i = 1; i < 7; ++i)
    if (i < ra.nseg && blk >= ra.start[i]) seg = i;
  const float* src = ra.src[seg];
  u16* dst = ra.dst[seg];
  const int O = ra.O[seg];
  int idx = (blk - ra.start[seg]) * 256 + threadIdx.x;
  if (idx >= O * 128) return;
  int o = idx >> 7, c8 = idx & 127;
  const float* s = src + (size_t)o * 9216 + (size_t)c8 * 72;
  float v[72];
#pragma unroll
  for (int i = 0; i < 18; ++i) {
    float4 f = *(const float4*)(s + i * 4);
    v[i * 4 + 0] = f.x; v[i * 4 + 1] = f.y; v[i * 4 + 2] = f.z; v[i * 4 + 3] = f.w;
  }
#pragma unroll
  for (int t = 0; t < 9; ++t) {
    union { uint4 u; u16 h[8]; } pk;
#pragma unroll
    for (int j = 0; j < 8; ++j) pk.h[j] = f2bf(v[j * 9 + t]);
    *(uint4*)(dst + ((size_t)t * O + o) * 1024 + c8 * 8) = pk.u;
  }
}

// ---------------- deformable bilinear sampling (device body) ----------------
__device__ __forceinline__
void sample_body(int k, int lp, int pix0, int Npc,
                 const u16* __restrict__ featP, const float* __restrict__ offp,
                 u16* __restrict__ spl, int tid) {
  const int p = pix0 + lp;
  const int c8 = tid & 15;
  int b = p / HW, hw = p - b * HW;
  int h = hw / 80, w = hw - h * 80;
  float dy = offp[p * 27 + k];
  float dx = offp[p * 27 + 9 + k];
  float ml = offp[p * 27 + 18 + k];
  float m = 1.f / (1.f + expf(-ml));
  float py = (float)(h - 1 + k / 3) + dy;
  float px = (float)(w - 1 + (k % 3)) + dx;
  float y0f = floorf(py), x0f = floorf(px);
  float wy1 = py - y0f, wx1 = px - x0f;
  float wy0 = 1.f - wy1, wx0 = 1.f - wx1;
  int y0 = (int)y0f, x0 = (int)x0f;
  int ya = min(max(y0, -1), 18),  yb = min(max(y0 + 1, -1), 18);
  int xa = min(max(x0, -1), 80),  xb = min(max(x0 + 1, -1), 80);
  const u16* base = featP + (size_t)b * PBAT;
  const u16* r00 = base + ((size_t)(ya + 1) * 82 + (xa + 1)) * 1024;
  const u16* r01 = base + ((size_t)(ya + 1) * 82 + (xb + 1)) * 1024;
  const u16* r10 = base + ((size_t)(yb + 1) * 82 + (xa + 1)) * 1024;
  const u16* r11 = base + ((size_t)(yb + 1) * 82 + (xb + 1)) * 1024;
  float w00 = wy0 * wx0 * m, w01 = wy0 * wx1 * m;
  float w10 = wy1 * wx0 * m, w11 = wy1 * wx1 * m;
  u16* dst = spl + ((size_t)k * Npc + lp) * 1024;
  for (int c = c8 * 8; c < 1024; c += 128) {
    union { uint4 u; u16 h[8]; } a, bq, cq2, d, o;
    a.u   = *(const uint4*)(r00 + c);
    bq.u  = *(const uint4*)(r01 + c);
    cq2.u = *(const uint4*)(r10 + c);
    d.u   = *(const uint4*)(r11 + c);
#pragma unroll
    for (int j = 0; j < 8; ++j) {
      float v = w00 * bf2f(a.h[j]) + w01 * bf2f(bq.h[j]) +
                w10 * bf2f(cq2.h[j]) + w11 * bf2f(d.h[j]);
      o.h[j] = f2bf(v);
    }
    *(uint4*)(dst + c) = o.u;
  }
}

__global__ __launch_bounds__(256)
void sample_standalone(const u16* __restrict__ featP, const float* __restrict__ offp,
                       u16* __restrict__ spl, int pix0, int Npc) {
  sample_body(blockIdx.y, blockIdx.x * 16 + (threadIdx.x >> 4), pix0, Npc,
              featP, offp, spl, threadIdx.x);
}

// FLAGS: 1 = planes-B, 2 = store fp32 flat [p][Co], 4 = BN, 8 = ReLU
struct Job {
  const u16* W; const u16* B;
  const float* bias; const float* bng; const float* bnb;
  void* out; int Co; int pix0; int Npc;
};

constexpr int LDSU16  = 16384;  // 32 KB: drain body (sampler-co-scheduled kernels)
constexpr int LDSU16B = 32768;  // 64 KB: 2-buffer body (gemm_dual only)

// ---------------- shared addressing setup ----------------
struct GemmAddr {
  int aoff[2], boff[2];
  int wm, wn, frm, kq, sel, wv;
};

template<bool PLANES>
__device__ __forceinline__ GemmAddr gemm_addr(const Job& J, int px, int oy) {
  GemmAddr G;
  const int tid = threadIdx.x;
  G.wv = tid >> 6;
  const int lane = tid & 63;
  const int o0 = oy * 128;
  const int p0 = J.pix0 + px * 128;
  const int lr = lane >> 2;
  const int qs = (lane & 3) ^ ((lane >> 3) & 3);
#pragma unroll
  for (int s = 0; s < 2; ++s) {
    int r = (G.wv * 2 + s) * 16 + lr;
    int o = min(o0 + r, J.Co - 1);
    G.aoff[s] = o * 1024 + qs * 8;
    int p = p0 + r;
    if (PLANES) {
      G.boff[s] = (p - J.pix0) * 1024 + qs * 8;
    } else {
      int b = p / HW, hw = p - b * HW;
      int h = hw / 80, w = hw - h * 80;
      G.boff[s] = ((b * 20 + h) * 82 + w) * 1024 + qs * 8;
    }
  }
  G.wm = G.wv >> 1; G.wn = G.wv & 1;
  G.frm = lane & 15; G.kq = lane >> 4;
  G.sel = (G.kq ^ ((lane >> 1) & 3)) * 16;
  return G;
}

// epilogue shared by both bodies
template<int FLAGS>
__device__ __forceinline__ void gemm_epilogue(const Job& J, const GemmAddr& G,
                                              f32x4 (&acc)[4][4], int px, int oy) {
  constexpr bool F32OUT  = (FLAGS & 2) != 0;
  constexpr bool HASBN   = (FLAGS & 4) != 0;
  constexpr bool HASRELU = (FLAGS & 8) != 0;
  const int o0 = oy * 128;
  const int p0 = J.pix0 + px * 128;
  size_t obase[4];
#pragma unroll
  for (int j = 0; j < 4; ++j) {
    int pn = p0 + G.wn * 64 + j * 16 + G.frm;
    if (F32OUT) {
      obase[j] = (size_t)pn * J.Co;
    } else {
      int b = pn / HW, hw = pn - b * HW;
      int h = hw / 80, w = hw - h * 80;
      obase[j] = ((size_t)(b * 20 + h + 1) * 82 + (w + 1)) * 1024;
    }
  }
#pragma unroll
  for (int i = 0; i < 4; ++i) {
    int o = o0 + G.wm * 64 + i * 16 + G.kq * 4;
    float bi[4], sc[4], sh[4];
#pragma unroll
    for (int r = 0; r < 4; ++r) {
      int oc = min(o + r, J.Co - 1);
      bi[r] = J.bias[oc];
      if (HASBN) { sc[r] = J.bng[oc] * rsqrtf(1.f + 1e-5f); sh[r] = J.bnb[oc]; }
    }
#pragma unroll
    for (int j = 0; j < 4; ++j) {
      float v[4];
#pragma unroll
      for (int r = 0; r < 4; ++r) {
        float x = acc[i][j][r] + bi[r];
        if (HASBN) x = x * sc[r] + sh[r];
        if (HASRELU) x = fmaxf(x, 0.f);
        v[r] = x;
      }
      if (F32OUT) {
        float* op = (float*)J.out;
#pragma unroll
        for (int r = 0; r < 4; ++r)
          if (o + r < J.Co) op[obase[j] + o + r] = v[r];
      } else {
        u16* op = (u16*)J.out;
        ushort4 pk;
        pk.x = f2bf(v[0]); pk.y = f2bf(v[1]); pk.z = f2bf(v[2]); pk.w = f2bf(v[3]);
        *(ushort4*)(op + obase[j] + o) = pk;
      }
    }
  }
}

// ---------------- 128x128 drain MFMA body, BK=64, 32 KB (R7 verified) ----------------
template<int FLAGS>
__device__ __forceinline__ void gemm_body(const Job J, u16* lds, int px, int oy) {
  constexpr bool PLANES = (FLAGS & 1) != 0;
  u16* As = lds;
  u16* Bs = lds + 8192;
  GemmAddr G = gemm_addr<PLANES>(J, px, oy);
  u16* aDst = As + (G.wv * 2) * 512;
  u16* bDst = Bs + (G.wv * 2) * 512;

  f32x4 acc[4][4];
#pragma unroll
  for (int i = 0; i < 4; ++i)
#pragma unroll
    for (int j = 0; j < 4; ++j) acc[i][j] = (f32x4)0.f;

  for (int t = 0; t < 9; ++t) {
    const u16* Wt = J.W + (size_t)t * J.Co * 1024;
    const u16* Bt = J.B + (PLANES ? (size_t)t * (size_t)J.Npc * 1024
                                  : (size_t)(((t / 3) * 82 + (t % 3)) * 1024));
    for (int cc = 0; cc < 1024; cc += 64) {
      __syncthreads();
#pragma unroll
      for (int s2 = 0; s2 < 2; ++s2)
#pragma unroll
        for (int s = 0; s < 2; ++s) {
          __builtin_amdgcn_global_load_lds(GAS(Wt + G.aoff[s] + cc + s2 * 32),
                                           LAS(aDst + s2 * 4096 + s * 512), 16, 0, 0);
          __builtin_amdgcn_global_load_lds(GAS(Bt + G.boff[s] + cc + s2 * 32),
                                           LAS(bDst + s2 * 4096 + s * 512), 16, 0, 0);
        }
      __syncthreads();
#pragma unroll
      for (int s2 = 0; s2 < 2; ++s2) {
        const char* Ab = (const char*)As + s2 * 8192;
        const char* Bb = (const char*)Bs + s2 * 8192;
        uint4 af[4], bf4[4];
#pragma unroll
        for (int i = 0; i < 4; ++i) {
          af[i]  = *(const uint4*)(Ab + (G.wm * 64 + i * 16 + G.frm) * 64 + G.sel);
          bf4[i] = *(const uint4*)(Bb + (G.wn * 64 + i * 16 + G.frm) * 64 + G.sel);
        }
#pragma unroll
        for (int i = 0; i < 4; ++i) {
          short8 a = __builtin_bit_cast(short8, af[i]);
#pragma unroll
          for (int j = 0; j < 4; ++j) {
            short8 b = __builtin_bit_cast(short8, bf4[j]);
            acc[i][j] = __builtin_amdgcn_mfma_f32_16x16x32_bf16(a, b, acc[i][j], 0, 0, 0);
          }
        }
      }
    }
  }
  gemm_epilogue<FLAGS>(J, G, acc, px, oy);
}

// ------- 128x128 2-buffer stage-ahead body, BK=64, 64 KB (gemm_dual only) -------
// Per K-step: STAGE(buf^1, k+1) BEFORE compute(buf) -> load latency hides under
// ds_read+MFMA; one vmcnt(0) + ONE barrier per step (vs 2 barriers + blind drain).
template<int FLAGS>
__device__ __forceinline__ void gemm_body2(const Job J, u16* lds, int px, int oy) {
  constexpr bool PLANES = (FLAGS & 1) != 0;
  GemmAddr G = gemm_addr<PLANES>(J, px, oy);

  f32x4 acc[4][4];
#pragma unroll
  for (int i = 0; i < 4; ++i)
#pragma unroll
    for (int j = 0; j < 4; ++j) acc[i][j] = (f32x4)0.f;

  // buffer BUF in {0,1}: A at u16 BUF*16384, B at BUF*16384 + 8192
#define G2_STAGE(BUF, KT)                                                       \
  { int t_ = (KT) >> 4, cc_ = ((KT) & 15) << 6;                                 \
    const u16* Wt_ = J.W + (size_t)t_ * (size_t)J.Co * 1024 + cc_;              \
    const u16* Bt_ = J.B + (PLANES ? (size_t)t_ * (size_t)J.Npc * 1024          \
                     : (size_t)(((t_ / 3) * 82 + (t_ % 3)) * 1024)) + cc_;      \
    u16* aD_ = lds + (BUF) * 16384 + (G.wv * 2) * 512;                          \
    u16* bD_ = lds + (BUF) * 16384 + 8192 + (G.wv * 2) * 512;                   \
    _Pragma("unroll") for (int s2_ = 0; s2_ < 2; ++s2_)                         \
    _Pragma("unroll") for (int s_ = 0; s_ < 2; ++s_) {                          \
      __builtin_amdgcn_global_load_lds(GAS(Wt_ + G.aoff[s_] + s2_ * 32),        \
                                       LAS(aD_ + s2_ * 4096 + s_ * 512), 16, 0, 0); \
      __builtin_amdgcn_global_load_lds(GAS(Bt_ + G.boff[s_] + s2_ * 32),        \
                                       LAS(bD_ + s2_ * 4096 + s_ * 512), 16, 0, 0); } }

#define G2_MMA(BUF)                                                             \
  { _Pragma("unroll") for (int s2 = 0; s2 < 2; ++s2) {                          \
      const char* Ab = (const char*)lds + (BUF) * 32768 + s2 * 8192;            \
      const char* Bb = (const char*)lds + (BUF) * 32768 + 16384 + s2 * 8192;    \
      uint4 af[4], bf4[4];                                                      \
      _Pragma("unroll") for (int i = 0; i < 4; ++i) {                           \
        af[i]  = *(const uint4*)(Ab + (G.wm * 64 + i * 16 + G.frm) * 64 + G.sel); \
        bf4[i] = *(const uint4*)(Bb + (G.wn * 64 + i * 16 + G.frm) * 64 + G.sel); } \
      _Pragma("unroll") for (int i = 0; i < 4; ++i) {                           \
        short8 a = __builtin_bit_cast(short8, af[i]);                           \
        _Pragma("unroll") for (int j = 0; j < 4; ++j) {                         \
          short8 b = __builtin_bit_cast(short8, bf4[j]);                        \
          acc[i][j] = __builtin_amdgcn_mfma_f32_16x16x32_bf16(a, b, acc[i][j], 0, 0, 0); } } } }

#define G2_SYNC                                                                 \
  asm volatile("s_waitcnt vmcnt(0)" ::: "memory");                              \
  __builtin_amdgcn_s_barrier();                                                 \
  asm volatile("" ::: "memory");

  // prologue: stage k=0 into buf0
  G2_STAGE(0, 0)
  G2_SYNC

  // 144 K-steps (9 taps x 16), 2 per iteration for compile-time buffer indices
  for (int kt2 = 0; kt2 < 72; ++kt2) {
    const int kt = kt2 * 2;
    G2_STAGE(1, kt + 1)
    G2_MMA(0)
    G2_SYNC
    if (kt2 < 71) { G2_STAGE(0, kt + 2) }
    G2_MMA(1)
    G2_SYNC
  }

#undef G2_STAGE
#undef G2_MMA
#undef G2_SYNC

  gemm_epilogue<FLAGS>(J, G, acc, px, oy);
}

template<int F0, int F1>
__global__ __launch_bounds__(256)
void gemm_dual(Job j0, Job j1, int ysplit) {
  __shared__ __align__(16) u16 lds[LDSU16B];
  // px-major XCD clustering: virt = px*NY + y
  int id = blockIdx.y * gridDim.x + blockIdx.x;
  int virt = xcd_virt(id, gridDim.x * gridDim.y);
  int NY = gridDim.y;
  int px = virt / NY, y = virt % NY;
  if (y < ysplit) gemm_body2<F0>(j0, lds, px, y);
  else            gemm_body2<F1>(j1, lds, px, y - ysplit);
}

// GEMM job co-scheduled with sampler blocks (16 px each). grid.x = n0 + 9*(nps/16).
// Keeps the 32 KB drain body: a 64 KB static LDS would halve sampler occupancy.
template<int F0>
__global__ __launch_bounds__(256)
void gemm_sample(Job j, const u16* __restrict__ featP, const float* __restrict__ offp,
                 u16* __restrict__ spl, int n0, int pix0s, int nps) {
  __shared__ __align__(16) u16 lds[LDSU16];
  int gx = blockIdx.x;
  if (gx < n0) {
    int virt = xcd_virt(gx, n0);         // n0 = 720: px-major over (90 px, 8 oy)
    gemm_body<F0>(j, lds, virt >> 3, virt & 7);
  } else {
    int sidx = gx - n0;
    int per = nps >> 4;
    int k = sidx / per, bs = sidx % per;
    sample_body(k, bs * 16 + ((int)threadIdx.x >> 4), pix0s, nps,
                featP, offp, spl, (int)threadIdx.x);
  }
}

// dcn chunk kernel: [n0: dcn gemm blocks][n1: cls3 head blocks][rest: sampler chunk t+1]
template<int F0, int F1>
__global__ __launch_bounds__(256)
void dcn_chunk(Job j0, Job j1, int n0, int nt0, int n1,
               const u16* __restrict__ featP, const float* __restrict__ offp,
               u16* __restrict__ splNext, int pix0n, int npn) {
  __shared__ __align__(16) u16 lds[LDSU16];
  int x = blockIdx.x;
  if (x < n0) {
    int virt = xcd_virt(x, n0);          // n0 = nt0*8: px-major (px = v/8, oy = v%8)
    gemm_body<F0>(j0, lds, virt >> 3, virt & 7);
    return;
  }
  x -= n0;
  if (x < n1) { gemm_body<F1>(j1, lds, x % 90, x / 90); return; }
  x -= n1;
  int per = npn >> 4;                 // sampler blocks per tap (16 px each)
  int k = x / per, bs = x % per;
  sample_body(k, bs * 16 + ((int)threadIdx.x >> 4), pix0n, npn,
              featP, offp, splNext, (int)threadIdx.x);
}

} // namespace

extern "C" void kernel_launch(void* const* d_in, const int* in_sizes, int n_in,
                              void* d_out, int out_size, void* d_ws, size_t ws_size,
                              hipStream_t stream) {
  const float* feat   = (const float*)d_in[0];
  const float* cls_w1 = (const float*)d_in[1];
  const float* cls_b1 = (const float*)d_in[2];
  const float* cls_w2 = (const float*)d_in[3];
  const float* cls_b2 = (const float*)d_in[4];
  const float* cls_w3 = (const float*)d_in[5];
  const float* cls_b3 = (const float*)d_in[6];
  const float* off_w  = (const float*)d_in[7];
  const float* off_b  = (const float*)d_in[8];
  const float* dcn_w  = (const float*)d_in[9];
  const float* dcn_b  = (const float*)d_in[10];
  const float* bn1_g  = (const float*)d_in[11];
  const float* bn1_b  = (const float*)d_in[12];
  const float* reg_w2 = (const float*)d_in[13];
  const float* reg_b2 = (const float*)d_in[14];
  const float* bn2_g  = (const float*)d_in[15];
  const float* bn2_b  = (const float*)d_in[16];
  const float* reg_w3 = (const float*)d_in[17];
  const float* reg_b3 = (const float*)d_in[18];
  float* outp = (float*)d_out;

  const size_t ACTB = 26869760;                // 8*20*82*1024*2 bytes
  char* wsb = (char*)d_ws;
  u16* featP = (u16*)(wsb);
  u16* bufA  = (u16*)(wsb + ACTB);
  u16* bufB  = (u16*)(wsb + 2 * ACTB);
  u16* wts   = (u16*)(wsb + 3 * ACTB);
  float* offp = (float*)(wsb + 3 * ACTB + 85432320);
  u16* spl   = (u16*)(wsb + 3 * ACTB + 85432320 + 1244160);
  const size_t BASE = 3 * ACTB + 85432320 + 1244160;   // 167,285,760
  const size_t SPLB = (size_t)9 * 11520 * 1024 * 2;    // 212,336,640

  u16* offT = wts;
  u16* w1T  = wts + 248832;
  u16* w2T  = wts + 9686016;
  u16* w3T  = wts + 19123200;
  u16* dcnT = wts + 20007936;
  u16* r2T  = wts + 29445120;
  u16* r3T  = wts + 38882304;

  dim3 blk(256);

  hipMemsetAsync(featP, 0, 3 * ACTB, stream);
  transpose_feat<<<dim3(40, 144), blk, 0, stream>>>(feat, featP);

  {
    RepackArgs ra;
    const float* s[7] = {off_w, cls_w1, cls_w2, cls_w3, dcn_w, reg_w2, reg_w3};
    u16* d[7] = {offT, w1T, w2T, w3T, dcnT, r2T, r3T};
    int  O[7] = {27, 1024, 1024, 96, 1024, 1024, 416};
    int acc = 0;
    for (int i = 0; i < 7; ++i) {
      ra.src[i] = s[i]; ra.dst[i] = d[i]; ra.O[i] = O[i]; ra.start[i] = acc;
      acc += (O[i] * 128 + 255) / 256;
    }
    ra.nseg = 7;
    repack_all<<<dim3(acc), blk, 0, stream>>>(ra);
  }

  Job jOff  = {offT, featP, off_b, nullptr, nullptr, offp, 27, 0, 0};
  Job jCls1 = {w1T, featP, cls_b1, nullptr, nullptr, bufA, 1024, 0, 0};
  Job jCls2 = {w2T, bufA, cls_b2, nullptr, nullptr, bufB, 1024, 0, 0};
  Job jCls3 = {w3T, bufB, cls_b3, nullptr, nullptr, outp, 96, 0, 0};
  Job jReg2 = {r2T, bufA, reg_b2, bn2_g, bn2_b, bufB, 1024, 0, 0};
  Job jReg3 = {r3T, bufB, reg_b3, nullptr, nullptr, outp + 1105920, 416, 0, 0};

  size_t avail = ws_size > BASE ? ws_size - BASE : 0;

  // pick chunk size (in 128-px tiles) for ping-pong sampling; 0 = doesn't fit
  int tch = 0;
  {
    const int cand[5] = {30, 18, 15, 10, 9};
    for (int i = 0; i < 5; ++i)
      if ((size_t)2 * cand[i] * 2359296 <= avail) { tch = cand[i]; break; }
  }

  // D2: cls1 (relu->bf16, y<8) + offset conv (f32 flat, y==8; shares featP B)
  gemm_dual<8, 2><<<dim3(90, 9), blk, 0, stream>>>(jCls1, jOff, 8);

  if (avail >= SPLB) {
    // ---- tier 1: full spl fits ----
    gemm_sample<8><<<dim3(720 + 6480), blk, 0, stream>>>(jCls2, featP, offp, spl, 720, 0, 11520);
    Job jDcn = {dcnT, spl, dcn_b, bn1_g, bn1_b, bufA, 1024, 0, 11520};
    gemm_dual<1 | 4 | 8, 2><<<dim3(90, 9), blk, 0, stream>>>(jDcn, jCls3, 8);
    gemm_dual<4 | 8, 4 | 8><<<dim3(90, 8), blk, 0, stream>>>(jReg2, jReg2, 8);
    gemm_dual<2, 2><<<dim3(90, 4), blk, 0, stream>>>(jReg3, jReg3, 4);
  } else if (tch > 0) {
    // ---- tier 2: chunked ping-pong sampling ----
    const int C = 90 / tch;
    const int np = tch * 128;
    u16* splA = spl;
    u16* splB = spl + (size_t)tch * 1179648;   // elements

    // D3: cls2 (720) + sample chunk0 -> splA
    gemm_sample<8><<<dim3(720 + 9 * (np / 16)), blk, 0, stream>>>(
        jCls2, featP, offp, splA, 720, 0, np);
    // chunk loop: dcn chunk i (+cls3 in chunk0) + sample chunk i+1
    for (int i = 0; i < C; ++i) {
      u16* sCur  = (i & 1) ? splB : splA;
      u16* sNext = (i & 1) ? splA : splB;
      Job jDcnC = {dcnT, sCur, dcn_b, bn1_g, bn1_b, bufA, 1024, i * np, np};
      int n0 = tch * 8;
      int n1 = (i == 0) ? 90 : 0;
      bool hasS = (i + 1 < C);
      int ns = hasS ? 9 * (np / 16) : 0;
      dcn_chunk<1 | 4 | 8, 2><<<dim3(n0 + n1 + ns), blk, 0, stream>>>(
          jDcnC, jCls3, n0, tch, n1,
          featP, offp, sNext, (i + 1) * np, hasS ? np : 16);
    }
    gemm_dual<4 | 8, 4 | 8><<<dim3(90, 8), blk, 0, stream>>>(jReg2, jReg2, 8);
    gemm_dual<2, 2><<<dim3(90, 4), blk, 0, stream>>>(jReg3, jReg3, 4);
  } else {
    // ---- tier 3: serial chunked fallback ----
    gemm_dual<8, 8><<<dim3(90, 8), blk, 0, stream>>>(jCls2, jCls2, 8);
    int tiles = (int)(avail / 2359296);
    if (tiles < 1) tiles = 1;
    if (tiles > 90) tiles = 90;
    for (int t0 = 0; t0 < 90; t0 += tiles) {
      int nt = (90 - t0) < tiles ? (90 - t0) : tiles;
      int pix0 = t0 * 128, npp = nt * 128;
      sample_standalone<<<dim3(nt * 8, 9), blk, 0, stream>>>(featP, offp, spl, pix0, npp);
      Job jDcn = {dcnT, spl, dcn_b, bn1_g, bn1_b, bufA, 1024, pix0, npp};
      gemm_dual<1 | 4 | 8, 1 | 4 | 8><<<dim3(nt, 8), blk, 0, stream>>>(jDcn, jDcn, 8);
    }
    gemm_dual<2, 2><<<dim3(90, 1), blk, 0, stream>>>(jCls3, jCls3, 1);
    gemm_dual<4 | 8, 4 | 8><<<dim3(90, 8), blk, 0, stream>>>(jReg2, jReg2, 8);
    gemm_dual<2, 2><<<dim3(90, 4), blk, 0, stream>>>(jReg3, jReg3, 4);
  }
}

// Round 9
// 1841.105 us; speedup vs baseline: 1.1892x; 1.1892x over previous
//
#include <hip/hip_runtime.h>
#include <math.h>

typedef short short8 __attribute__((ext_vector_type(8)));
typedef float f32x4 __attribute__((ext_vector_type(4)));
typedef unsigned short u16;
typedef unsigned int u32;

#define GAS(p) ((__attribute__((address_space(1))) void*)(p))
#define LAS(p) ((__attribute__((address_space(3))) void*)(p))

namespace {

constexpr int HW   = 1440;           // 18*80
constexpr int PBAT = 20 * 82 * 1024; // padded per-batch elems

__device__ __forceinline__ u16 f2bf(float f) {
  u32 u = __float_as_uint(f);
  return (u16)((u + 0x7FFFu + ((u >> 16) & 1u)) >> 16);
}
__device__ __forceinline__ float bf2f(u16 h) {
  return __uint_as_float(((u32)h) << 16);
}

// XCD-aware bijective remap (m204): dispatch id -> virt; each of 8 XCDs
// (id%8 under round-robin) owns a CONTIGUOUS virt range, decoded px-major:
// the 8-9 B-panel sharers (same px, diff oy) land co-XCD => B fetched ~once.
// (R6 verified: FETCH 958->222 MB.)
__device__ __forceinline__ int xcd_virt(int id, int N) {
  int q = N >> 3, r = N & 7;
  int xcd = id & 7, pos = id >> 3;
  return (xcd < r ? xcd * (q + 1) : r * (q + 1) + (xcd - r) * q) + pos;
}

// ---------------- NCHW fp32 -> padded NHWC bf16 ----------------
__global__ __launch_bounds__(256)
void transpose_feat(const float* __restrict__ src, u16* __restrict__ dst) {
  __shared__ float tile[128][17];
  const int bh = blockIdx.y;            // 0..143
  const int b = bh / 18, h = bh % 18;
  const int wt = blockIdx.x % 5, ct = blockIdx.x / 5;
  const int w0 = wt * 16, c0 = ct * 128;
  const int tid = threadIdx.x;
#pragma unroll
  for (int it = 0; it < 8; ++it) {
    int idx = it * 256 + tid;
    int c = idx >> 4, w = idx & 15;
    tile[c][w] = src[((size_t)(b * 1024 + c0 + c) * 18 + h) * 80 + w0 + w];
  }
  __syncthreads();
  const int px = tid >> 4, cq = tid & 15;
  union { uint4 u; u16 s[8]; } pk;
#pragma unroll
  for (int j = 0; j < 8; ++j) pk.s[j] = f2bf(tile[cq * 8 + j][px]);
  *(uint4*)(dst + ((size_t)(b * 20 + h + 1) * 82 + (w0 + px + 1)) * 1024 + c0 + cq * 8) = pk.u;
}

// ---------------- merged weight repack: 7 tensors in one dispatch ----------------
struct RepackArgs {
  const float* src[7];
  u16* dst[7];
  int O[7];
  int start[7];
  int nseg;
};

__global__ __launch_bounds__(256)
void repack_all(RepackArgs ra) {
  int blk = blockIdx.x;
  int seg = 0;
#pragma unroll
  for (int i = 1; i < 7; ++i)
    if (i < ra.nseg && blk >= ra.start[i]) seg = i;
  const float* src = ra.src[seg];
  u16* dst = ra.dst[seg];
  const int O = ra.O[seg];
  int idx = (blk - ra.start[seg]) * 256 + threadIdx.x;
  if (idx >= O * 128) return;
  int o = idx >> 7, c8 = idx & 127;
  const float* s = src + (size_t)o * 9216 + (size_t)c8 * 72;
  float v[72];
#pragma unroll
  for (int i = 0; i < 18; ++i) {
    float4 f = *(const float4*)(s + i * 4);
    v[i * 4 + 0] = f.x; v[i * 4 + 1] = f.y; v[i * 4 + 2] = f.z; v[i * 4 + 3] = f.w;
  }
#pragma unroll
  for (int t = 0; t < 9; ++t) {
    union { uint4 u; u16 h[8]; } pk;
#pragma unroll
    for (int j = 0; j < 8; ++j) pk.h[j] = f2bf(v[j * 9 + t]);
    *(uint4*)(dst + ((size_t)t * O + o) * 1024 + c8 * 8) = pk.u;
  }
}

// ---------------- offset prep: per (tap,pixel) corner offsets + weights ----------------
// Mirrors the old sample_body math exactly (incl. clamped corners into the
// zero-padded featP border and sigmoid-premultiplied bilinear weights).
__global__ __launch_bounds__(256)
void prep_off(const float* __restrict__ offp, u32* __restrict__ prep) {
  int idx = blockIdx.x * 256 + threadIdx.x;      // [0, 9*11520)
  if (idx >= 9 * 11520) return;
  int k = idx / 11520, p = idx - k * 11520;
  int b = p / HW, hw = p - b * HW;
  int h = hw / 80, w = hw - h * 80;
  float dy = offp[p * 27 + k];
  float dx = offp[p * 27 + 9 + k];
  float ml = offp[p * 27 + 18 + k];
  float m = 1.f / (1.f + expf(-ml));
  float py = (float)(h - 1 + k / 3) + dy;
  float px = (float)(w - 1 + (k % 3)) + dx;
  float y0f = floorf(py), x0f = floorf(px);
  float wy1 = py - y0f, wx1 = px - x0f;
  float wy0 = 1.f - wy1, wx0 = 1.f - wx1;
  int y0 = (int)y0f, x0 = (int)x0f;
  int ya = min(max(y0, -1), 18),  yb = min(max(y0 + 1, -1), 18);
  int xa = min(max(x0, -1), 80),  xb = min(max(x0 + 1, -1), 80);
  u32 base = (u32)b * PBAT;
  uint4 ov;
  ov.x = base + ((u32)(ya + 1) * 82 + (u32)(xa + 1)) * 1024;
  ov.y = base + ((u32)(ya + 1) * 82 + (u32)(xb + 1)) * 1024;
  ov.z = base + ((u32)(yb + 1) * 82 + (u32)(xa + 1)) * 1024;
  ov.w = base + ((u32)(yb + 1) * 82 + (u32)(xb + 1)) * 1024;
  float4 wv4;
  wv4.x = wy0 * wx0 * m; wv4.y = wy0 * wx1 * m;
  wv4.z = wy1 * wx0 * m; wv4.w = wy1 * wx1 * m;
  u32* dst = prep + (size_t)idx * 8;
  *(uint4*)dst = ov;
  *(float4*)(dst + 4) = wv4;
}

// FLAGS: 2 = store fp32 flat [p][Co], 4 = BN, 8 = ReLU, 16 = fused deformable B
struct Job {
  const u16* W; const u16* B;      // B: activation buffer, or featP when FUSED
  const float* bias; const float* bng; const float* bnb;
  void* out; int Co; int pix0; int Npc;
  const u32* prep;                 // FUSED only
};

constexpr int LDSU16 = 16384;  // 32 KB shared block: As = lds[0..8192), Bs = lds[8192..)

// ---------------- shared addressing setup ----------------
struct GemmAddr {
  int aoff[2], boff[2];
  int wm, wn, frm, kq, sel, wv;
};

__device__ __forceinline__ GemmAddr gemm_addr(const Job& J, int px, int oy) {
  GemmAddr G;
  const int tid = threadIdx.x;
  G.wv = tid >> 6;
  const int lane = tid & 63;
  const int o0 = oy * 128;
  const int p0 = J.pix0 + px * 128;
  const int lr = lane >> 2;
  const int qs = (lane & 3) ^ ((lane >> 3) & 3);
#pragma unroll
  for (int s = 0; s < 2; ++s) {
    int r = (G.wv * 2 + s) * 16 + lr;
    int o = min(o0 + r, J.Co - 1);
    G.aoff[s] = o * 1024 + qs * 8;
    int p = p0 + r;
    int b = p / HW, hw = p - b * HW;
    int h = hw / 80, w = hw - h * 80;
    G.boff[s] = ((b * 20 + h) * 82 + w) * 1024 + qs * 8;
  }
  G.wm = G.wv >> 1; G.wn = G.wv & 1;
  G.frm = lane & 15; G.kq = lane >> 4;
  G.sel = (G.kq ^ ((lane >> 1) & 3)) * 16;
  return G;
}

template<int FLAGS>
__device__ __forceinline__ void gemm_epilogue(const Job& J, const GemmAddr& G,
                                              f32x4 (&acc)[4][4], int px, int oy) {
  constexpr bool F32OUT  = (FLAGS & 2) != 0;
  constexpr bool HASBN   = (FLAGS & 4) != 0;
  constexpr bool HASRELU = (FLAGS & 8) != 0;
  const int o0 = oy * 128;
  const int p0 = J.pix0 + px * 128;
  size_t obase[4];
#pragma unroll
  for (int j = 0; j < 4; ++j) {
    int pn = p0 + G.wn * 64 + j * 16 + G.frm;
    if (F32OUT) {
      obase[j] = (size_t)pn * J.Co;
    } else {
      int b = pn / HW, hw = pn - b * HW;
      int h = hw / 80, w = hw - h * 80;
      obase[j] = ((size_t)(b * 20 + h + 1) * 82 + (w + 1)) * 1024;
    }
  }
#pragma unroll
  for (int i = 0; i < 4; ++i) {
    int o = o0 + G.wm * 64 + i * 16 + G.kq * 4;
    float bi[4], sc[4], sh[4];
#pragma unroll
    for (int r = 0; r < 4; ++r) {
      int oc = min(o + r, J.Co - 1);
      bi[r] = J.bias[oc];
      if (HASBN) { sc[r] = J.bng[oc] * rsqrtf(1.f + 1e-5f); sh[r] = J.bnb[oc]; }
    }
#pragma unroll
    for (int j = 0; j < 4; ++j) {
      float v[4];
#pragma unroll
      for (int r = 0; r < 4; ++r) {
        float x = acc[i][j][r] + bi[r];
        if (HASBN) x = x * sc[r] + sh[r];
        if (HASRELU) x = fmaxf(x, 0.f);
        v[r] = x;
      }
      if (F32OUT) {
        float* op = (float*)J.out;
#pragma unroll
        for (int r = 0; r < 4; ++r)
          if (o + r < J.Co) op[obase[j] + o + r] = v[r];
      } else {
        u16* op = (u16*)J.out;
        ushort4 pk;
        pk.x = f2bf(v[0]); pk.y = f2bf(v[1]); pk.z = f2bf(v[2]); pk.w = f2bf(v[3]);
        *(ushort4*)(op + obase[j] + o) = pk;
      }
    }
  }
}

// ---------------- 128x128 drain MFMA body, BK=64, 32 KB (R7 verified) ----------------
// FUSED variant: B-tile is computed on the fly (bilinear blend of 4 featP corner
// rows via prep table) and ds_write'd into the exact LDS slots the
// global_load_lds path would have produced. No spl materialization.
template<int FLAGS>
__device__ __forceinline__ void gemm_body(const Job J, u16* lds, int px, int oy) {
  constexpr bool FUSED = (FLAGS & 16) != 0;
  u16* As = lds;
  u16* Bs = lds + 8192;
  GemmAddr G = gemm_addr(J, px, oy);
  u16* aDst = As + (G.wv * 2) * 512;
  u16* bDst = Bs + (G.wv * 2) * 512;

  const int tid = threadIdx.x;
  const int lane = tid & 63;
  const int lr = lane >> 2;
  const int qs8 = ((lane & 3) ^ ((lane >> 3) & 3)) * 8;
  const int p0 = J.pix0 + px * 128;

  f32x4 acc[4][4];
#pragma unroll
  for (int i = 0; i < 4; ++i)
#pragma unroll
    for (int j = 0; j < 4; ++j) acc[i][j] = (f32x4)0.f;

  for (int t = 0; t < 9; ++t) {
    const u16* Wt = J.W + (size_t)t * J.Co * 1024;
    const u16* Bt = J.B + (size_t)(((t / 3) * 82 + (t % 3)) * 1024);
    uint4 po[2]; float4 pw[2];
    if (FUSED) {
#pragma unroll
      for (int s = 0; s < 2; ++s) {
        int p = p0 + (G.wv * 2 + s) * 16 + lr;
        const u32* pr = J.prep + ((size_t)t * 11520 + p) * 8;
        po[s] = *(const uint4*)pr;
        pw[s] = *(const float4*)(pr + 4);
      }
    }
    for (int cc = 0; cc < 1024; cc += 64) {
      __syncthreads();
#pragma unroll
      for (int s2 = 0; s2 < 2; ++s2)
#pragma unroll
        for (int s = 0; s < 2; ++s) {
          __builtin_amdgcn_global_load_lds(GAS(Wt + G.aoff[s] + cc + s2 * 32),
                                           LAS(aDst + s2 * 4096 + s * 512), 16, 0, 0);
          if (!FUSED)
            __builtin_amdgcn_global_load_lds(GAS(Bt + G.boff[s] + cc + s2 * 32),
                                             LAS(bDst + s2 * 4096 + s * 512), 16, 0, 0);
        }
      if (FUSED) {
        const u16* fp = J.B;   // featP
#pragma unroll
        for (int s = 0; s < 2; ++s)
#pragma unroll
          for (int s2 = 0; s2 < 2; ++s2) {
            int chb = cc + s2 * 32 + qs8;
            union { uint4 u; u16 h[8]; } c0, c1, c2, c3, ob;
            c0.u = *(const uint4*)(fp + po[s].x + chb);
            c1.u = *(const uint4*)(fp + po[s].y + chb);
            c2.u = *(const uint4*)(fp + po[s].z + chb);
            c3.u = *(const uint4*)(fp + po[s].w + chb);
#pragma unroll
            for (int j = 0; j < 8; ++j) {
              float v = pw[s].x * bf2f(c0.h[j]) + pw[s].y * bf2f(c1.h[j]) +
                        pw[s].z * bf2f(c2.h[j]) + pw[s].w * bf2f(c3.h[j]);
              ob.h[j] = f2bf(v);
            }
            *(uint4*)(Bs + s2 * 4096 + (G.wv * 2 + s) * 512 + lane * 8) = ob.u;
          }
      }
      __syncthreads();
#pragma unroll
      for (int s2 = 0; s2 < 2; ++s2) {
        const char* Ab = (const char*)As + s2 * 8192;
        const char* Bb = (const char*)Bs + s2 * 8192;
        uint4 af[4], bf4[4];
#pragma unroll
        for (int i = 0; i < 4; ++i) {
          af[i]  = *(const uint4*)(Ab + (G.wm * 64 + i * 16 + G.frm) * 64 + G.sel);
          bf4[i] = *(const uint4*)(Bb + (G.wn * 64 + i * 16 + G.frm) * 64 + G.sel);
        }
#pragma unroll
        for (int i = 0; i < 4; ++i) {
          short8 a = __builtin_bit_cast(short8, af[i]);
#pragma unroll
          for (int j = 0; j < 4; ++j) {
            short8 b = __builtin_bit_cast(short8, bf4[j]);
            acc[i][j] = __builtin_amdgcn_mfma_f32_16x16x32_bf16(a, b, acc[i][j], 0, 0, 0);
          }
        }
      }
    }
  }
  gemm_epilogue<FLAGS>(J, G, acc, px, oy);
}

template<int F0, int F1>
__global__ __launch_bounds__(256)
void gemm_dual(Job j0, Job j1, int ysplit) {
  __shared__ __align__(16) u16 lds[LDSU16];
  // px-major XCD clustering: virt = px*NY + y
  int id = blockIdx.y * gridDim.x + blockIdx.x;
  int virt = xcd_virt(id, gridDim.x * gridDim.y);
  int NY = gridDim.y;
  int px = virt / NY, y = virt % NY;
  if (y < ysplit) gemm_body<F0>(j0, lds, px, y);
  else            gemm_body<F1>(j1, lds, px, y - ysplit);
}

} // namespace

extern "C" void kernel_launch(void* const* d_in, const int* in_sizes, int n_in,
                              void* d_out, int out_size, void* d_ws, size_t ws_size,
                              hipStream_t stream) {
  const float* feat   = (const float*)d_in[0];
  const float* cls_w1 = (const float*)d_in[1];
  const float* cls_b1 = (const float*)d_in[2];
  const float* cls_w2 = (const float*)d_in[3];
  const float* cls_b2 = (const float*)d_in[4];
  const float* cls_w3 = (const float*)d_in[5];
  const float* cls_b3 = (const float*)d_in[6];
  const float* off_w  = (const float*)d_in[7];
  const float* off_b  = (const float*)d_in[8];
  const float* dcn_w  = (const float*)d_in[9];
  const float* dcn_b  = (const float*)d_in[10];
  const float* bn1_g  = (const float*)d_in[11];
  const float* bn1_b  = (const float*)d_in[12];
  const float* reg_w2 = (const float*)d_in[13];
  const float* reg_b2 = (const float*)d_in[14];
  const float* bn2_g  = (const float*)d_in[15];
  const float* bn2_b  = (const float*)d_in[16];
  const float* reg_w3 = (const float*)d_in[17];
  const float* reg_b3 = (const float*)d_in[18];
  float* outp = (float*)d_out;

  const size_t ACTB = 26869760;                // 8*20*82*1024*2 bytes
  char* wsb = (char*)d_ws;
  u16* featP = (u16*)(wsb);
  u16* bufA  = (u16*)(wsb + ACTB);
  u16* bufB  = (u16*)(wsb + 2 * ACTB);
  u16* wts   = (u16*)(wsb + 3 * ACTB);
  float* offp = (float*)(wsb + 3 * ACTB + 85432320);
  u32* prep  = (u32*)(wsb + 3 * ACTB + 85432320 + 1244160);  // 3.32 MB (was spl)

  u16* offT = wts;
  u16* w1T  = wts + 248832;
  u16* w2T  = wts + 9686016;
  u16* w3T  = wts + 19123200;
  u16* dcnT = wts + 20007936;
  u16* r2T  = wts + 29445120;
  u16* r3T  = wts + 38882304;

  dim3 blk(256);

  hipMemsetAsync(featP, 0, 3 * ACTB, stream);
  transpose_feat<<<dim3(40, 144), blk, 0, stream>>>(feat, featP);

  {
    RepackArgs ra;
    const float* s[7] = {off_w, cls_w1, cls_w2, cls_w3, dcn_w, reg_w2, reg_w3};
    u16* d[7] = {offT, w1T, w2T, w3T, dcnT, r2T, r3T};
    int  O[7] = {27, 1024, 1024, 96, 1024, 1024, 416};
    int acc = 0;
    for (int i = 0; i < 7; ++i) {
      ra.src[i] = s[i]; ra.dst[i] = d[i]; ra.O[i] = O[i]; ra.start[i] = acc;
      acc += (O[i] * 128 + 255) / 256;
    }
    ra.nseg = 7;
    repack_all<<<dim3(acc), blk, 0, stream>>>(ra);
  }

  Job jOff  = {offT, featP, off_b, nullptr, nullptr, offp, 27, 0, 0, nullptr};
  Job jCls1 = {w1T, featP, cls_b1, nullptr, nullptr, bufA, 1024, 0, 0, nullptr};
  Job jCls2 = {w2T, bufA, cls_b2, nullptr, nullptr, bufB, 1024, 0, 0, nullptr};
  Job jCls3 = {w3T, bufB, cls_b3, nullptr, nullptr, outp, 96, 0, 0, nullptr};
  Job jDcn  = {dcnT, featP, dcn_b, bn1_g, bn1_b, bufA, 1024, 0, 0, prep};
  Job jReg2 = {r2T, bufA, reg_b2, bn2_g, bn2_b, bufB, 1024, 0, 0, nullptr};
  Job jReg3 = {r3T, bufB, reg_b3, nullptr, nullptr, outp + 1105920, 416, 0, 0, nullptr};

  // D2: cls1 (relu->bf16, y<8) + offset conv (f32 flat, y==8; shares featP B)
  gemm_dual<8, 2><<<dim3(90, 9), blk, 0, stream>>>(jCls1, jOff, 8);
  // P: per-(tap,pixel) corner offsets + sigmoid-premultiplied bilinear weights
  prep_off<<<dim3(405), blk, 0, stream>>>(offp, prep);
  // D3: cls2
  gemm_dual<8, 8><<<dim3(90, 8), blk, 0, stream>>>(jCls2, jCls2, 8);
  // D4: dcn with FUSED deformable sampling (y<8) + cls head (f32, y==8)
  gemm_dual<16 | 4 | 8, 2><<<dim3(90, 9), blk, 0, stream>>>(jDcn, jCls3, 8);
  // D5: reg2 (bufA -> bufB, bn+relu)
  gemm_dual<4 | 8, 4 | 8><<<dim3(90, 8), blk, 0, stream>>>(jReg2, jReg2, 8);
  // D6: reg3 head (f32 flat)
  gemm_dual<2, 2><<<dim3(90, 4), blk, 0, stream>>>(jReg3, jReg3, 4);
}